// Round 7
// baseline (59.454 us; speedup 1.0000x reference)
//
#include <hip/hip_runtime.h>
#include <math.h>

#define D_MODEL 128
#define D_STATE 64
#define VOCAB 2000
#define SEQ_L 4096
#define BATCH 32
#define SEG 32                   // j's per weights BLOCK (16 per half-block)
#define SEGH 16
#define LN_BLOCKS (VOCAB / 4)    // 500
#define W_BLOCKS (SEQ_L / SEG)   // 128
#define JGRP 8                   // j-groups per reduce block
#define JPER (SEQ_L / JGRP)      // 512 j's per group
#define LN_EPS 1e-5f

// ============ Kernel 1: fused prep (LN-embed ∥ pooled-conv weights) =========
// blocks [0, 500): layernorm 4 vocab rows each -> e_ln
// blocks [500, 628): Wv[j,m] = D_m + sum_n r_mn * (1 - q_mn^{L-j}),
//   q = exp(dt_m*A_n), r = C_mn/(1-q), geometric recurrence over SEGH j's.
// No inter-block communication, single writer per output word.
__global__ __launch_bounds__(256) void prep_kernel(
    const float* __restrict__ emb, const float* __restrict__ ln_w,
    const float* __restrict__ ln_b, const float* __restrict__ A_log,
    const float* __restrict__ Dp, const float* __restrict__ C_re,
    const float* __restrict__ log_dt, float* __restrict__ e_ln,
    float* __restrict__ Wv) {
  if (blockIdx.x < LN_BLOCKS) {
    int v = blockIdx.x * 4 + (threadIdx.x >> 6);
    int t = threadIdx.x & 63;
    const float* row = emb + v * D_MODEL;
    float h0 = row[t];
    float h1 = row[t + 64];
    float s = h0 + h1;
#pragma unroll
    for (int off = 32; off; off >>= 1) s += __shfl_xor(s, off);
    float mu = s * (1.0f / D_MODEL);
    float d0 = h0 - mu, d1 = h1 - mu;
    float q = d0 * d0 + d1 * d1;
#pragma unroll
    for (int off = 32; off; off >>= 1) q += __shfl_xor(q, off);
    float var = q * (1.0f / D_MODEL);
    float rs = rsqrtf(var + LN_EPS);
    e_ln[v * D_MODEL + t]      = d0 * rs * ln_w[t]      + ln_b[t];
    e_ln[v * D_MODEL + t + 64] = d1 * rs * ln_w[t + 64] + ln_b[t + 64];
  } else {
    __shared__ float Ash[D_STATE];
    if (threadIdx.x < D_STATE) Ash[threadIdx.x] = -expf(A_log[threadIdx.x]);
    __syncthreads();
    int wb = blockIdx.x - LN_BLOCKS;
    int m = threadIdx.x & (D_MODEL - 1);
    int sub = threadIdx.x >> 7;               // 0 or 1
    int j0 = wb * SEG + sub * SEGH;
    float acc[SEGH];
#pragma unroll
    for (int k = 0; k < SEGH; ++k) acc[k] = 0.0f;
    float dt = expf(log_dt[m]);
    float bs = 0.0f;
    float r1_end = (float)(SEQ_L - j0 - (SEGH - 1));
    for (int n = 0; n < D_STATE; ++n) {
      float x = dt * Ash[n];                  // negative
      float q = expf(x);
      float r = C_re[m * D_STATE + n] / (1.0f - q);
      bs += r;
      float g = expf(x * r1_end);             // q^{L - j0 - 15}
      acc[SEGH - 1] += r * g;
#pragma unroll
      for (int jj = SEGH - 2; jj >= 0; --jj) {
        g *= q;
        acc[jj] += r * g;
      }
    }
    float base = Dp[m] + bs;
#pragma unroll
    for (int k = 0; k < SEGH; ++k)
      Wv[(j0 + k) * D_MODEL + m] = base - acc[k];
  }
}

// ============ Kernel 2: per-batch-row reduce + classifier (single writer) ===
// Block b (1024 thr = 16 waves): p[m] = sum_j e_ln[x[b,j],m] * Wv[j,m],
// classifier dot in-block, out[b*2+{0,1}] written by thread 0 only.
// Fully deterministic: fixed reduction tree, no atomics, no cross-block comm.
__global__ __launch_bounds__(1024) void batch_reduce_kernel(
    const int* __restrict__ x, const float* __restrict__ e_ln,
    const float* __restrict__ Wv, const float* __restrict__ W_cls,
    const float* __restrict__ b_cls, float* __restrict__ out) {
  __shared__ int toks[SEQ_L];        // 16 KB
  __shared__ float sm[16][2];
  int b = blockIdx.x;
  int tid = threadIdx.x;
  const int* xrow = x + b * SEQ_L;
#pragma unroll
  for (int i = 0; i < SEQ_L / 1024; ++i)
    toks[tid + i * 1024] = xrow[tid + i * 1024];
  __syncthreads();
  int m = tid & (D_MODEL - 1);
  int grp = tid >> 7;                // 0..7
  int j0 = grp * JPER;
  float a0 = 0.0f, a1 = 0.0f, a2 = 0.0f, a3 = 0.0f;
#pragma unroll 4
  for (int j = j0; j < j0 + JPER; j += 4) {
    int t0 = toks[j], t1 = toks[j + 1], t2 = toks[j + 2], t3 = toks[j + 3];
    float e0 = e_ln[t0 * D_MODEL + m];
    float e1 = e_ln[t1 * D_MODEL + m];
    float e2 = e_ln[t2 * D_MODEL + m];
    float e3 = e_ln[t3 * D_MODEL + m];
    float w0 = Wv[(j + 0) * D_MODEL + m];
    float w1 = Wv[(j + 1) * D_MODEL + m];
    float w2 = Wv[(j + 2) * D_MODEL + m];
    float w3 = Wv[(j + 3) * D_MODEL + m];
    a0 = fmaf(e0, w0, a0);
    a1 = fmaf(e1, w1, a1);
    a2 = fmaf(e2, w2, a2);
    a3 = fmaf(e3, w3, a3);
  }
  float p = (a0 + a1) + (a2 + a3);
  float v0 = p * W_cls[m];
  float v1 = p * W_cls[D_MODEL + m];
#pragma unroll
  for (int off = 32; off; off >>= 1) {
    v0 += __shfl_xor(v0, off);
    v1 += __shfl_xor(v1, off);
  }
  int wave = tid >> 6;
  if ((tid & 63) == 0) {
    sm[wave][0] = v0;
    sm[wave][1] = v1;
  }
  __syncthreads();
  if (tid < 16) {
    float u0 = sm[tid][0];
    float u1 = sm[tid][1];
#pragma unroll
    for (int off = 8; off; off >>= 1) {
      u0 += __shfl_xor(u0, off);
      u1 += __shfl_xor(u1, off);
    }
    if (tid == 0) {
      out[b * 2 + 0] = u0 * (1.0f / SEQ_L) + b_cls[0];
      out[b * 2 + 1] = u1 * (1.0f / SEQ_L) + b_cls[1];
    }
  }
}

extern "C" void kernel_launch(void* const* d_in, const int* in_sizes, int n_in,
                              void* d_out, int out_size, void* d_ws, size_t ws_size,
                              hipStream_t stream) {
  const int*   x      = (const int*)d_in[0];
  const float* emb    = (const float*)d_in[1];
  const float* ln_w   = (const float*)d_in[2];
  const float* ln_b   = (const float*)d_in[3];
  const float* A_log  = (const float*)d_in[4];
  const float* Dp     = (const float*)d_in[5];
  const float* C_re   = (const float*)d_in[6];
  const float* log_dt = (const float*)d_in[7];
  const float* W_cls  = (const float*)d_in[8];
  const float* b_cls  = (const float*)d_in[9];
  float* out = (float*)d_out;

  char* ws = (char*)d_ws;
  float* e_ln = (float*)(ws);                 // 2000*128*4 = 1,024,000 B
  float* Wv   = (float*)(ws + 1048576);       // 4096*128*4 = 2,097,152 B

  prep_kernel<<<LN_BLOCKS + W_BLOCKS, 256, 0, stream>>>(
      emb, ln_w, ln_b, A_log, Dp, C_re, log_dt, e_ln, Wv);
  batch_reduce_kernel<<<BATCH, 1024, 0, stream>>>(
      x, e_ln, Wv, W_cls, b_cls, out);
}

// Round 10
// 28.532 us; speedup vs baseline: 2.0838x; 2.0838x over previous
//
#include <hip/hip_runtime.h>
#include <math.h>

#define D_MODEL 128
#define D_STATE 64
#define VOCAB 2000
#define SEQ_L 4096
#define BATCH 32
#define BGRP 2                   // batch rows per reduce block (Wv reuse)
#define NBG (BATCH / BGRP)       // 16
#define JSPLIT 64                // chunks per batch row
#define CHUNK (SEQ_L / JSPLIT)   // 64 j's per chunk
#define SEG 32                   // weights: j's per block (16 per half)
#define SEGH 16
#define LN_BLOCKS (VOCAB / 4)    // 500
#define W_BLOCKS (SEQ_L / SEG)   // 128 (blocks 500..627)
#define LN_EPS 1e-5f

// ============ Kernel 1: fused prep (LN-embed ∥ pooled-conv weights) =========
// blocks [0, 500): layernorm 4 vocab rows each -> e_ln
// blocks [500, 628): Wv[j,m] = D_m + sum_n r_mn * (1 - q_mn^{L-j}),
//   q = exp(dt_m*A_n), r = C_mn/(1-q), geometric recurrence over SEGH j's.
__global__ __launch_bounds__(256) void prep_kernel(
    const float* __restrict__ emb, const float* __restrict__ ln_w,
    const float* __restrict__ ln_b, const float* __restrict__ A_log,
    const float* __restrict__ Dp, const float* __restrict__ C_re,
    const float* __restrict__ log_dt, float* __restrict__ e_ln,
    float* __restrict__ Wv) {
  if (blockIdx.x < LN_BLOCKS) {
    int v = blockIdx.x * 4 + (threadIdx.x >> 6);
    int t = threadIdx.x & 63;
    const float* row = emb + v * D_MODEL;
    float h0 = row[t];
    float h1 = row[t + 64];
    float s = h0 + h1;
#pragma unroll
    for (int off = 32; off; off >>= 1) s += __shfl_xor(s, off);
    float mu = s * (1.0f / D_MODEL);
    float d0 = h0 - mu, d1 = h1 - mu;
    float q = d0 * d0 + d1 * d1;
#pragma unroll
    for (int off = 32; off; off >>= 1) q += __shfl_xor(q, off);
    float var = q * (1.0f / D_MODEL);
    float rs = rsqrtf(var + LN_EPS);
    e_ln[v * D_MODEL + t]      = d0 * rs * ln_w[t]      + ln_b[t];
    e_ln[v * D_MODEL + t + 64] = d1 * rs * ln_w[t + 64] + ln_b[t + 64];
  } else {
    __shared__ float Ash[D_STATE];
    if (threadIdx.x < D_STATE) Ash[threadIdx.x] = -expf(A_log[threadIdx.x]);
    __syncthreads();
    int wb = blockIdx.x - LN_BLOCKS;
    int m = threadIdx.x & (D_MODEL - 1);
    int sub = threadIdx.x >> 7;               // 0 or 1
    int j0 = wb * SEG + sub * SEGH;
    float acc[SEGH];
#pragma unroll
    for (int k = 0; k < SEGH; ++k) acc[k] = 0.0f;
    float dt = expf(log_dt[m]);
    float bs = 0.0f;
    float r1_end = (float)(SEQ_L - j0 - (SEGH - 1));
    for (int n = 0; n < D_STATE; ++n) {
      float x = dt * Ash[n];                  // negative
      float q = expf(x);
      float r = C_re[m * D_STATE + n] / (1.0f - q);
      bs += r;
      float g = expf(x * r1_end);             // q^{L - j0 - 15}
      acc[SEGH - 1] += r * g;
#pragma unroll
      for (int jj = SEGH - 2; jj >= 0; --jj) {
        g *= q;
        acc[jj] += r * g;
      }
    }
    float base = Dp[m] + bs;
#pragma unroll
    for (int k = 0; k < SEGH; ++k)
      Wv[(j0 + k) * D_MODEL + m] = base - acc[k];
  }
}

// ============ Kernel 2: gather-reduce + in-block classifier =================
// Block (bg, s): for 2 batch rows b = bg*2+{0,1}:
//   p_b[m] = sum_{j in chunk s} e_ln[x[b,j], m] * Wv[j, m]   (Wv loaded once)
//   pc[(b*JSPLIT+s)*2+c] = sum_m p_b[m] * W_cls[c, m]
// Fixed reduction tree, one writer per pc word, no atomics.
__global__ __launch_bounds__(128) void reduce_kernel(
    const int* __restrict__ x, const float* __restrict__ e_ln,
    const float* __restrict__ Wv, const float* __restrict__ W_cls,
    float* __restrict__ pc) {
  __shared__ int toks[BGRP][CHUNK];
  __shared__ float sm[2][4];
  int bg = blockIdx.x;
  int sIdx = blockIdx.y;
  int tid = threadIdx.x;           // = m, 0..127
  if (tid < CHUNK) {
    toks[0][tid] = x[(bg * BGRP + 0) * SEQ_L + sIdx * CHUNK + tid];
  } else {
    toks[1][tid - CHUNK] = x[(bg * BGRP + 1) * SEQ_L + sIdx * CHUNK + (tid - CHUNK)];
  }
  __syncthreads();
  int m = tid;
  const float* wbase = Wv + (sIdx * CHUNK) * D_MODEL + m;
  float a00 = 0.0f, a01 = 0.0f, a10 = 0.0f, a11 = 0.0f;
#pragma unroll
  for (int j = 0; j < CHUNK; j += 2) {
    float w0 = wbase[(j + 0) * D_MODEL];
    float w1 = wbase[(j + 1) * D_MODEL];
    int t00 = toks[0][j], t01 = toks[0][j + 1];
    int t10 = toks[1][j], t11 = toks[1][j + 1];
    float e00 = e_ln[t00 * D_MODEL + m];
    float e01 = e_ln[t01 * D_MODEL + m];
    float e10 = e_ln[t10 * D_MODEL + m];
    float e11 = e_ln[t11 * D_MODEL + m];
    a00 = fmaf(e00, w0, a00);
    a01 = fmaf(e01, w1, a01);
    a10 = fmaf(e10, w0, a10);
    a11 = fmaf(e11, w1, a11);
  }
  float p0 = a00 + a01;            // batch row bg*2+0
  float p1 = a10 + a11;            // batch row bg*2+1
  float wc0 = W_cls[m], wc1 = W_cls[D_MODEL + m];
  float v00 = p0 * wc0, v01 = p0 * wc1;
  float v10 = p1 * wc0, v11 = p1 * wc1;
#pragma unroll
  for (int off = 32; off; off >>= 1) {
    v00 += __shfl_xor(v00, off);
    v01 += __shfl_xor(v01, off);
    v10 += __shfl_xor(v10, off);
    v11 += __shfl_xor(v11, off);
  }
  int wave = tid >> 6;
  if ((tid & 63) == 0) {
    sm[wave][0] = v00; sm[wave][1] = v01;
    sm[wave][2] = v10; sm[wave][3] = v11;
  }
  __syncthreads();
  if (tid == 0) {
    int b0 = bg * BGRP;
    pc[((b0 + 0) * JSPLIT + sIdx) * 2 + 0] = sm[0][0] + sm[1][0];
    pc[((b0 + 0) * JSPLIT + sIdx) * 2 + 1] = sm[0][1] + sm[1][1];
    pc[((b0 + 1) * JSPLIT + sIdx) * 2 + 0] = sm[0][2] + sm[1][2];
    pc[((b0 + 1) * JSPLIT + sIdx) * 2 + 1] = sm[0][3] + sm[1][3];
  }
}

// ============ Kernel 3: final combine (one block, single writer) ============
// pc[b][s][2] -> out[b][2]; thread groups of 32 per b, shfl tree, lane0 writes.
__global__ __launch_bounds__(1024) void final_kernel(
    const float* __restrict__ pc, const float* __restrict__ b_cls,
    float* __restrict__ out) {
  int tid = threadIdx.x;
  int b = tid >> 5;                // 0..31
  int k = tid & 31;                // 0..31
  float v0 = pc[(b * JSPLIT + k) * 2 + 0] + pc[(b * JSPLIT + k + 32) * 2 + 0];
  float v1 = pc[(b * JSPLIT + k) * 2 + 1] + pc[(b * JSPLIT + k + 32) * 2 + 1];
#pragma unroll
  for (int off = 16; off; off >>= 1) {
    v0 += __shfl_xor(v0, off);     // stays within the 32-lane b-group
    v1 += __shfl_xor(v1, off);
  }
  if (k == 0) {
    out[b * 2 + 0] = v0 * (1.0f / SEQ_L) + b_cls[0];
    out[b * 2 + 1] = v1 * (1.0f / SEQ_L) + b_cls[1];
  }
}

extern "C" void kernel_launch(void* const* d_in, const int* in_sizes, int n_in,
                              void* d_out, int out_size, void* d_ws, size_t ws_size,
                              hipStream_t stream) {
  const int*   x      = (const int*)d_in[0];
  const float* emb    = (const float*)d_in[1];
  const float* ln_w   = (const float*)d_in[2];
  const float* ln_b   = (const float*)d_in[3];
  const float* A_log  = (const float*)d_in[4];
  const float* Dp     = (const float*)d_in[5];
  const float* C_re   = (const float*)d_in[6];
  const float* log_dt = (const float*)d_in[7];
  const float* W_cls  = (const float*)d_in[8];
  const float* b_cls  = (const float*)d_in[9];
  float* out = (float*)d_out;

  char* ws = (char*)d_ws;
  float* e_ln = (float*)(ws);                 // 2000*128*4 = 1,024,000 B
  float* Wv   = (float*)(ws + 1048576);       // 4096*128*4 = 2,097,152 B
  float* pc   = (float*)(ws + 3145728);       // 32*64*2*4  = 16,384 B

  prep_kernel<<<LN_BLOCKS + W_BLOCKS, 256, 0, stream>>>(
      emb, ln_w, ln_b, A_log, Dp, C_re, log_dt, e_ln, Wv);
  reduce_kernel<<<dim3(NBG, JSPLIT), 128, 0, stream>>>(
      x, e_ln, Wv, W_cls, pc);
  final_kernel<<<1, 1024, 0, stream>>>(pc, b_cls, out);
}